// Round 12
// baseline (89.202 us; speedup 1.0000x reference)
//
#include <hip/hip_runtime.h>
#include <stdint.h>

#define N_G   1024
#define H_IMG 128
#define W_IMG 128
#define TILE  8
#define TILES_X (W_IMG / TILE)            // 16
#define N_TILES (TILES_X * (H_IMG/TILE))  // 256
#define NT    512                          // 8 waves/block -> 2 waves/SIMD (R9 measured best)
#define CHUNK 256                          // sorted records staged per blend pass
#define FXc   128.0f
#define FYc   128.0f

// One dispatch, zero inter-block communication (grid barriers ~40us each on
// multi-XCD CDNA — R5; extra dispatches ~13us each — R3/R4). Each block owns
// one 8x8 tile, redundantly recomputing per-gaussian data.
// R6: no dynamically-indexed private arrays (scratch spill).
// R7: blend reads sequential pre-gathered LDS; rank sort not bitonic.
// R8: sort/blend were not the cost — prep latency is.
// R9: fast rcp/rsq/log + NT=512 => BEST 84us.
// R10: SH-for-all-1024 = 10x shs traffic, regression. R11: NT=1024 slightly
// worse than 512. R12: R9 config + blend micro-fixes (ballot every 8, LDS
// prefetch of record j+1).
__global__ __launch_bounds__(NT) void gauss_tile_kernel(
    const float* __restrict__ means3D, const float* __restrict__ opac,
    const float* __restrict__ shs,     const float* __restrict__ scales,
    const float* __restrict__ rot,     const float* __restrict__ vm,
    const float* __restrict__ pm,      const float* __restrict__ campos,
    const float* __restrict__ bg,
    float* __restrict__ out)           // color (3,H,W) then radii (N_G)
{
    __shared__ float gxA[N_G], gyA[N_G], cAA[N_G], cBA[N_G], cCA[N_G], opA[N_G]; // 24 KB
    __shared__ unsigned long long svKeys[N_G];   // 8 KB  (survivors, arbitrary order)
    __shared__ int   ranks[N_G];                 // 4 KB
    __shared__ float srec[CHUNK * 12];           // 12 KB sorted AoS records
    __shared__ int   cnt, allDead;

    const int t   = threadIdx.x;
    const int bid = blockIdx.x;
    const int tx = bid & (TILES_X - 1), ty = bid / TILES_X;
    const float x0 = (float)(tx * TILE), x1 = x0 + (float)(TILE - 1);
    const float y0 = (float)(ty * TILE), y1 = y0 + (float)(TILE - 1);

    if (t == 0) { cnt = 0; allDead = 0; }
    __syncthreads();

    // ---------- Phase 1: prep all gaussians (2/thread) + inline cull ----------
    #pragma unroll
    for (int k = 0; k < N_G / NT; ++k) {
        const int n = k * NT + t;

        float mx = means3D[n*3+0], my = means3D[n*3+1], mz = means3D[n*3+2];
        float4 q = *(const float4*)(rot + n*4);
        float s0 = scales[n*3+0], s1 = scales[n*3+1], s2 = scales[n*3+2];
        float op = opac[n];

        float pv0   = mx*vm[0] + my*vm[4] + mz*vm[8]  + vm[12];
        float pv1   = mx*vm[1] + my*vm[5] + mz*vm[9]  + vm[13];
        float depth = mx*vm[2] + my*vm[6] + mz*vm[10] + vm[14];
        bool dvalid = depth > 0.2f;

        float ph0 = mx*pm[0] + my*pm[4] + mz*pm[8]  + pm[12];
        float ph1 = mx*pm[1] + my*pm[5] + mz*pm[9]  + pm[13];
        float ph3 = mx*pm[3] + my*pm[7] + mz*pm[11] + pm[15];
        float invw = __builtin_amdgcn_rcpf(ph3 + 1e-7f);
        float pp0 = ph0 * invw, pp1 = ph1 * invw;

        float qinv = __builtin_amdgcn_rsqf(q.x*q.x + q.y*q.y + q.z*q.z + q.w*q.w);
        float qr = q.x*qinv, qx = q.y*qinv, qy = q.z*qinv, qz = q.w*qinv;
        float R00 = 1.f - 2.f*(qy*qy + qz*qz), R01 = 2.f*(qx*qy - qr*qz), R02 = 2.f*(qx*qz + qr*qy);
        float R10 = 2.f*(qx*qy + qr*qz), R11 = 1.f - 2.f*(qx*qx + qz*qz), R12 = 2.f*(qy*qz - qr*qx);
        float R20 = 2.f*(qx*qz - qr*qy), R21 = 2.f*(qy*qz + qr*qx), R22 = 1.f - 2.f*(qx*qx + qy*qy);

        float M00=R00*s0, M01=R01*s1, M02=R02*s2;
        float M10=R10*s0, M11=R11*s1, M12=R12*s2;
        float M20=R20*s0, M21=R21*s1, M22=R22*s2;

        float S00 = M00*M00 + M01*M01 + M02*M02;
        float S01 = M00*M10 + M01*M11 + M02*M12;
        float S02 = M00*M20 + M01*M21 + M02*M22;
        float S11 = M10*M10 + M11*M11 + M12*M12;
        float S12 = M10*M20 + M11*M21 + M12*M22;
        float S22 = M20*M20 + M21*M21 + M22*M22;

        float tz   = dvalid ? depth : 1.0f;
        float itz  = __builtin_amdgcn_rcpf(tz);
        float txtz = fminf(fmaxf(pv0 * itz, -0.65f), 0.65f) * tz;
        float tytz = fminf(fmaxf(pv1 * itz, -0.65f), 0.65f) * tz;
        float J00 = FXc * itz, J02 = -FXc * txtz * itz * itz;
        float J11 = FYc * itz, J12 = -FYc * tytz * itz * itz;

        float T20k0 = J00*vm[0] + J02*vm[2];
        float T20k1 = J00*vm[4] + J02*vm[6];
        float T20k2 = J00*vm[8] + J02*vm[10];
        float T21k0 = J11*vm[1] + J12*vm[2];
        float T21k1 = J11*vm[5] + J12*vm[6];
        float T21k2 = J11*vm[9] + J12*vm[10];

        float U00 = T20k0*S00 + T20k1*S01 + T20k2*S02;
        float U01 = T20k0*S01 + T20k1*S11 + T20k2*S12;
        float U02 = T20k0*S02 + T20k1*S12 + T20k2*S22;
        float U10 = T21k0*S00 + T21k1*S01 + T21k2*S02;
        float U11 = T21k0*S01 + T21k1*S11 + T21k2*S12;
        float U12 = T21k0*S02 + T21k1*S12 + T21k2*S22;
        float cov00 = U00*T20k0 + U01*T20k1 + U02*T20k2;
        float cov01 = U00*T21k0 + U01*T21k1 + U02*T21k2;
        float cov11 = U10*T21k0 + U11*T21k1 + U12*T21k2;

        float a = cov00 + 0.3f, b = cov01, c = cov11 + 0.3f;
        float det = a*c - b*b;
        bool valid = dvalid && (det > 0.0f);
        float inv_det = (det > 0.0f) ? __builtin_amdgcn_rcpf(det) : 1.0f;

        float mid  = 0.5f * (a + c);
        // precise sqrtf: feeds the integer-compared radii output (ceil boundary)
        float lam1 = mid + sqrtf(fmaxf(0.1f, mid*mid - det));
        if (bid == 0)
            out[3*H_IMG*W_IMG + n] = valid ? ceilf(3.0f * sqrtf(lam1)) : 0.0f;

        float gx = ((pp0 + 1.0f) * (float)W_IMG - 1.0f) * 0.5f;
        float gy = ((pp1 + 1.0f) * (float)H_IMG - 1.0f) * 0.5f;

        gxA[n] = gx; gyA[n] = gy;
        cAA[n] = c * inv_det; cBA[n] = -b * inv_det; cCA[n] = a * inv_det;
        opA[n] = op;

        // conservative cull radius^2: alpha >= 1/255 needs |d|^2 <= 2 ln(255 op) lam1;
        // fast __logf safe under the 1.01x+1 margin.
        float op255 = op * 255.0f;
        float rc2 = (valid && op255 > 1.0f) ? (2.0f * __logf(op255) * lam1 * 1.01f + 1.0f)
                                            : -1.0f;   // always fails cull
        float cx = fminf(fmaxf(gx, x0), x1) - gx;
        float cy = fminf(fmaxf(gy, y0), y1) - gy;
        if (cx*cx + cy*cy <= rc2) {
            int slot = atomicAdd(&cnt, 1);
            // valid => depth>0.2 => positive float => bit order = value order
            svKeys[slot] = ((unsigned long long)__float_as_uint(depth) << 32) | (unsigned int)n;
        }
    }
    __syncthreads();
    const int M = cnt;

    // ---------- Phase 3: barrier-free rank sort (broadcast scan; keys unique) ----------
    // rank == position in the reference's stable depth argsort restricted to
    // this tile's survivors — exact.
    for (int s = t; s < M; s += NT) {
        unsigned long long key = svKeys[s];
        int r = 0;
        for (int j = 0; j < M; ++j)           // same j across threads -> LDS broadcast
            r += (svKeys[j] < key) ? 1 : 0;
        ranks[s] = r;
    }
    __syncthreads();

    // ---------- Phase 4: chunked sorted scatter (SH for survivors only) + blend ----------
    const float cpx = campos[0], cpy = campos[1], cpz = campos[2];
    const float bg0 = bg[0], bg1 = bg[1], bg2 = bg[2];
    const float px = x0 + (float)(t & (TILE - 1));
    const float py = y0 + (float)((t >> 3) & (TILE - 1));   // valid for t<64
    float T = 1.0f, Tfin = 1.0f, cr = 0.f, cg = 0.f, cb = 0.f;
    bool live = true;

    for (int base = 0; base < M; base += CHUNK) {
        for (int s = t; s < M; s += NT) {
            int r = ranks[s] - base;
            if (r >= 0 && r < CHUNK) {
                int idx = (int)(svKeys[s] & 0xFFFFFFFFu);

                // SH -> RGB for this survivor (constant-indexed, SROA-safe)
                float mx = means3D[idx*3+0], my = means3D[idx*3+1], mz = means3D[idx*3+2];
                float dxm = mx - cpx, dym = my - cpy, dzm = mz - cpz;
                float rinv = __builtin_amdgcn_rsqf(dxm*dxm + dym*dym + dzm*dzm);
                float sx = dxm*rinv, sy = dym*rinv, sz = dzm*rinv;
                float xx = sx*sx, yy = sy*sy, zz = sz*sz;
                float xy = sx*sy, yz = sy*sz, xz = sx*sz;
                float bb[16];
                bb[0]  = 0.28209479177387814f;
                bb[1]  = -0.4886025119029199f * sy;
                bb[2]  =  0.4886025119029199f * sz;
                bb[3]  = -0.4886025119029199f * sx;
                bb[4]  =  1.0925484305920792f * xy;
                bb[5]  = -1.0925484305920792f * yz;
                bb[6]  =  0.31539156525252005f * (2.f*zz - xx - yy);
                bb[7]  = -1.0925484305920792f * xz;
                bb[8]  =  0.5462742152960396f * (xx - yy);
                bb[9]  = -0.5900435899266435f * sy * (3.f*xx - yy);
                bb[10] =  2.890611442640554f  * xy * sz;
                bb[11] = -0.4570457994644658f * sy * (4.f*zz - xx - yy);
                bb[12] =  0.3731763325901154f * sz * (2.f*zz - 3.f*xx - 3.f*yy);
                bb[13] = -0.4570457994644658f * sx * (4.f*zz - xx - yy);
                bb[14] =  1.445305721320277f  * sz * (xx - yy);
                bb[15] = -0.5900435899266435f * sx * (xx - 3.f*yy);

                float acc0 = 0.f, acc1 = 0.f, acc2 = 0.f;
                const float4* sh4 = (const float4*)(shs + idx*48);
                #pragma unroll
                for (int u = 0; u < 12; ++u) {
                    float4 v = sh4[u];
                    const int f = 4*u;
                    if ((f+0)%3==0) acc0 += bb[(f+0)/3]*v.x; else if ((f+0)%3==1) acc1 += bb[(f+0)/3]*v.x; else acc2 += bb[(f+0)/3]*v.x;
                    if ((f+1)%3==0) acc0 += bb[(f+1)/3]*v.y; else if ((f+1)%3==1) acc1 += bb[(f+1)/3]*v.y; else acc2 += bb[(f+1)/3]*v.y;
                    if ((f+2)%3==0) acc0 += bb[(f+2)/3]*v.z; else if ((f+2)%3==1) acc1 += bb[(f+2)/3]*v.z; else acc2 += bb[(f+2)/3]*v.z;
                    if ((f+3)%3==0) acc0 += bb[(f+3)/3]*v.w; else if ((f+3)%3==1) acc1 += bb[(f+3)/3]*v.w; else acc2 += bb[(f+3)/3]*v.w;
                }

                float* rp = srec + r * 12;
                rp[0] = gxA[idx]; rp[1] = gyA[idx]; rp[2] = cAA[idx]; rp[3] = cBA[idx];
                rp[4] = cCA[idx]; rp[5] = opA[idx];
                rp[6] = fmaxf(acc0 + 0.5f, 0.f);
                rp[7] = fmaxf(acc1 + 0.5f, 0.f);
                rp[8] = fmaxf(acc2 + 0.5f, 0.f);
            }
        }
        __syncthreads();

        // blend: wave 0, sequential LDS reads with one-record prefetch;
        // ballot break-check every 8 records (live updates stay per-record exact)
        if (t < 64) {
            int nb = min(CHUNK, M - base);
            if (nb > 0) {
                float4 c0 = *(const float4*)(srec);
                float4 c1 = *(const float4*)(srec + 4);
                float  cb2 = srec[8];
                for (int j = 0; j < nb; ++j) {
                    float4 g0 = c0, g1 = c1;
                    float  b2 = cb2;
                    if (j + 1 < nb) {                      // prefetch next record
                        const float* gn = srec + (j + 1) * 12;
                        c0 = *(const float4*)(gn);
                        c1 = *(const float4*)(gn + 4);
                        cb2 = gn[8];
                    }
                    float dx = g0.x - px, dy = g0.y - py;
                    float power = -0.5f * (g0.z*dx*dx + g1.x*dy*dy) - g0.w*dx*dy;
                    float alpha = fminf(0.99f, g1.y * __expf(power));
                    if (live && power <= 0.0f && alpha >= (1.0f/255.0f)) {
                        float Tnew = T * (1.0f - alpha);
                        if (Tnew < 1e-4f) {
                            live = false;      // exact: ae_j and all later ae are 0
                        } else {
                            float w = T * alpha;
                            cr += w * g1.z; cg += w * g1.w; cb += w * b2;
                            Tfin *= (1.0f - alpha);
                            T = Tnew;
                        }
                    }
                    if (((j & 7) == 7) && __ballot(live) == 0ull) break;
                }
            }
            if (__ballot(live) == 0ull && t == 0) allDead = 1;
        }
        __syncthreads();
        if (allDead) break;                   // block-uniform after barrier
    }

    if (t < 64) {
        int p = (int)py * W_IMG + (int)px;
        out[p]                 = cr + bg0 * Tfin;
        out[H_IMG*W_IMG + p]   = cg + bg1 * Tfin;
        out[2*H_IMG*W_IMG + p] = cb + bg2 * Tfin;
    }
}

extern "C" void kernel_launch(void* const* d_in, const int* in_sizes, int n_in,
                              void* d_out, int out_size, void* d_ws, size_t ws_size,
                              hipStream_t stream) {
    const float* means3D = (const float*)d_in[0];
    const float* opac    = (const float*)d_in[2];
    const float* shs     = (const float*)d_in[3];
    const float* scales  = (const float*)d_in[4];
    const float* rot     = (const float*)d_in[5];
    const float* vm      = (const float*)d_in[6];
    const float* pm      = (const float*)d_in[7];
    const float* campos  = (const float*)d_in[8];
    const float* bg      = (const float*)d_in[9];

    gauss_tile_kernel<<<N_TILES, NT, 0, stream>>>(
        means3D, opac, shs, scales, rot, vm, pm, campos, bg, (float*)d_out);
}

// Round 13
// 85.799 us; speedup vs baseline: 1.0397x; 1.0397x over previous
//
#include <hip/hip_runtime.h>
#include <stdint.h>

#define N_G   1024
#define H_IMG 128
#define W_IMG 128
#define TILE  8
#define TILES_X (W_IMG / TILE)            // 16
#define N_TILES (TILES_X * (H_IMG/TILE))  // 256
#define NT    512                          // 8 waves/block -> 2 waves/SIMD (measured best: R9 vs R7/R11)
#define CHUNK 256                          // sorted records staged per blend pass
#define FXc   128.0f
#define FYc   128.0f

// FINAL (= R9, the measured optimum at 84.0us total / ~19us kernel).
// Architecture: one dispatch, zero inter-block communication. Each block owns
// one 8x8 tile and redundantly recomputes all per-gaussian data.
// Session-measured cost model (MI355X, this harness):
//   total = ~65us fixed (256MB ws re-poison fill ~40us + restores + graph
//           replay) + kernel. Kernel is latency-bound: no saturated pipe
//   (VALUBusy ~4%, HBM <1%, 0 bank conflicts) — cold-L2 loads + launch ramp.
// Lessons encoded here (each tested both directions):
//   R5:  grid-barrier spin ~40us/barrier on multi-XCD CDNA -> never fuse via flags.
//   R3/R4: extra dispatch ~13us -> single dispatch.
//   R6:  dynamically-indexed private arrays -> scratch spill; use LDS SoA.
//   R8:  bitonic->rank sort + sequential blend reads: neutral (weren't the cost).
//   R9:  fast rcp/rsq/log + NT=512: -4.4us (prep dependency chains WERE a cost).
//   R10: SH for all 1024 = 10x shs bytes on cold cache: +4us -> survivors only.
//   R11: NT=1024: +2.4us. R12: blend prefetch + batched ballot: +5us (compiler
//        already pipelines affine ds_reads; per-record exit saves work).
__global__ __launch_bounds__(NT) void gauss_tile_kernel(
    const float* __restrict__ means3D, const float* __restrict__ opac,
    const float* __restrict__ shs,     const float* __restrict__ scales,
    const float* __restrict__ rot,     const float* __restrict__ vm,
    const float* __restrict__ pm,      const float* __restrict__ campos,
    const float* __restrict__ bg,
    float* __restrict__ out)           // color (3,H,W) then radii (N_G)
{
    __shared__ float gxA[N_G], gyA[N_G], cAA[N_G], cBA[N_G], cCA[N_G], opA[N_G]; // 24 KB
    __shared__ unsigned long long svKeys[N_G];   // 8 KB  (survivors, arbitrary order)
    __shared__ int   ranks[N_G];                 // 4 KB
    __shared__ float srec[CHUNK * 12];           // 12 KB sorted AoS records
    __shared__ int   cnt, allDead;

    const int t   = threadIdx.x;
    const int bid = blockIdx.x;
    const int tx = bid & (TILES_X - 1), ty = bid / TILES_X;
    const float x0 = (float)(tx * TILE), x1 = x0 + (float)(TILE - 1);
    const float y0 = (float)(ty * TILE), y1 = y0 + (float)(TILE - 1);

    if (t == 0) { cnt = 0; allDead = 0; }
    __syncthreads();

    // ---------- Phase 1: prep all gaussians (2/thread) + inline cull ----------
    #pragma unroll
    for (int k = 0; k < N_G / NT; ++k) {
        const int n = k * NT + t;

        float mx = means3D[n*3+0], my = means3D[n*3+1], mz = means3D[n*3+2];

        float pv0   = mx*vm[0] + my*vm[4] + mz*vm[8]  + vm[12];
        float pv1   = mx*vm[1] + my*vm[5] + mz*vm[9]  + vm[13];
        float depth = mx*vm[2] + my*vm[6] + mz*vm[10] + vm[14];
        bool dvalid = depth > 0.2f;

        float ph0 = mx*pm[0] + my*pm[4] + mz*pm[8]  + pm[12];
        float ph1 = mx*pm[1] + my*pm[5] + mz*pm[9]  + pm[13];
        float ph3 = mx*pm[3] + my*pm[7] + mz*pm[11] + pm[15];
        float invw = __builtin_amdgcn_rcpf(ph3 + 1e-7f);
        float pp0 = ph0 * invw, pp1 = ph1 * invw;

        float4 q = *(const float4*)(rot + n*4);
        float qinv = __builtin_amdgcn_rsqf(q.x*q.x + q.y*q.y + q.z*q.z + q.w*q.w);
        float qr = q.x*qinv, qx = q.y*qinv, qy = q.z*qinv, qz = q.w*qinv;
        float R00 = 1.f - 2.f*(qy*qy + qz*qz), R01 = 2.f*(qx*qy - qr*qz), R02 = 2.f*(qx*qz + qr*qy);
        float R10 = 2.f*(qx*qy + qr*qz), R11 = 1.f - 2.f*(qx*qx + qz*qz), R12 = 2.f*(qy*qz - qr*qx);
        float R20 = 2.f*(qx*qz - qr*qy), R21 = 2.f*(qy*qz + qr*qx), R22 = 1.f - 2.f*(qx*qx + qy*qy);

        float s0 = scales[n*3+0], s1 = scales[n*3+1], s2 = scales[n*3+2];
        float M00=R00*s0, M01=R01*s1, M02=R02*s2;
        float M10=R10*s0, M11=R11*s1, M12=R12*s2;
        float M20=R20*s0, M21=R21*s1, M22=R22*s2;

        float S00 = M00*M00 + M01*M01 + M02*M02;
        float S01 = M00*M10 + M01*M11 + M02*M12;
        float S02 = M00*M20 + M01*M21 + M02*M22;
        float S11 = M10*M10 + M11*M11 + M12*M12;
        float S12 = M10*M20 + M11*M21 + M12*M22;
        float S22 = M20*M20 + M21*M21 + M22*M22;

        float tz   = dvalid ? depth : 1.0f;
        float itz  = __builtin_amdgcn_rcpf(tz);
        float txtz = fminf(fmaxf(pv0 * itz, -0.65f), 0.65f) * tz;
        float tytz = fminf(fmaxf(pv1 * itz, -0.65f), 0.65f) * tz;
        float J00 = FXc * itz, J02 = -FXc * txtz * itz * itz;
        float J11 = FYc * itz, J12 = -FYc * tytz * itz * itz;

        float T20k0 = J00*vm[0] + J02*vm[2];
        float T20k1 = J00*vm[4] + J02*vm[6];
        float T20k2 = J00*vm[8] + J02*vm[10];
        float T21k0 = J11*vm[1] + J12*vm[2];
        float T21k1 = J11*vm[5] + J12*vm[6];
        float T21k2 = J11*vm[9] + J12*vm[10];

        float U00 = T20k0*S00 + T20k1*S01 + T20k2*S02;
        float U01 = T20k0*S01 + T20k1*S11 + T20k2*S12;
        float U02 = T20k0*S02 + T20k1*S12 + T20k2*S22;
        float U10 = T21k0*S00 + T21k1*S01 + T21k2*S02;
        float U11 = T21k0*S01 + T21k1*S11 + T21k2*S12;
        float U12 = T21k0*S02 + T21k1*S12 + T21k2*S22;
        float cov00 = U00*T20k0 + U01*T20k1 + U02*T20k2;
        float cov01 = U00*T21k0 + U01*T21k1 + U02*T21k2;
        float cov11 = U10*T21k0 + U11*T21k1 + U12*T21k2;

        float a = cov00 + 0.3f, b = cov01, c = cov11 + 0.3f;
        float det = a*c - b*b;
        bool valid = dvalid && (det > 0.0f);
        float inv_det = (det > 0.0f) ? __builtin_amdgcn_rcpf(det) : 1.0f;

        float mid  = 0.5f * (a + c);
        // precise sqrtf: feeds the integer-compared radii output (ceil boundary)
        float lam1 = mid + sqrtf(fmaxf(0.1f, mid*mid - det));
        if (bid == 0)
            out[3*H_IMG*W_IMG + n] = valid ? ceilf(3.0f * sqrtf(lam1)) : 0.0f;

        float gx = ((pp0 + 1.0f) * (float)W_IMG - 1.0f) * 0.5f;
        float gy = ((pp1 + 1.0f) * (float)H_IMG - 1.0f) * 0.5f;
        float op = opac[n];

        gxA[n] = gx; gyA[n] = gy;
        cAA[n] = c * inv_det; cBA[n] = -b * inv_det; cCA[n] = a * inv_det;
        opA[n] = op;

        // conservative cull radius^2: alpha >= 1/255 needs |d|^2 <= 2 ln(255 op) lam1.
        // fast __logf is safe: the 1.01x + 1 margin dwarfs its ulp error.
        float op255 = op * 255.0f;
        float rc2 = (valid && op255 > 1.0f) ? (2.0f * __logf(op255) * lam1 * 1.01f + 1.0f)
                                            : -1.0f;   // always fails cull

        float cx = fminf(fmaxf(gx, x0), x1) - gx;
        float cy = fminf(fmaxf(gy, y0), y1) - gy;
        if (cx*cx + cy*cy <= rc2) {
            int slot = atomicAdd(&cnt, 1);
            // valid => depth>0.2 => positive float => bit order = value order
            svKeys[slot] = ((unsigned long long)__float_as_uint(depth) << 32) | (unsigned int)n;
        }
    }
    __syncthreads();
    const int M = cnt;

    // ---------- Phase 3: barrier-free rank sort (broadcast scan; keys unique) ----------
    // rank == position in the reference's stable depth argsort restricted to
    // this tile's survivors — exact.
    for (int s = t; s < M; s += NT) {
        unsigned long long key = svKeys[s];
        int r = 0;
        for (int j = 0; j < M; ++j)           // same j across threads -> LDS broadcast
            r += (svKeys[j] < key) ? 1 : 0;
        ranks[s] = r;
    }
    __syncthreads();

    // ---------- Phase 4: chunked sorted scatter (SH for survivors only) + blend ----------
    const float cpx = campos[0], cpy = campos[1], cpz = campos[2];
    const float px = x0 + (float)(t & (TILE - 1));
    const float py = y0 + (float)((t >> 3) & (TILE - 1));   // valid for t<64
    float T = 1.0f, Tfin = 1.0f, cr = 0.f, cg = 0.f, cb = 0.f;
    bool live = true;

    for (int base = 0; base < M; base += CHUNK) {
        for (int s = t; s < M; s += NT) {
            int r = ranks[s] - base;
            if (r >= 0 && r < CHUNK) {
                int idx = (int)(svKeys[s] & 0xFFFFFFFFu);

                // SH -> RGB for this survivor (constant-indexed, SROA-safe)
                float mx = means3D[idx*3+0], my = means3D[idx*3+1], mz = means3D[idx*3+2];
                float dxm = mx - cpx, dym = my - cpy, dzm = mz - cpz;
                float rinv = __builtin_amdgcn_rsqf(dxm*dxm + dym*dym + dzm*dzm);
                float sx = dxm*rinv, sy = dym*rinv, sz = dzm*rinv;
                float xx = sx*sx, yy = sy*sy, zz = sz*sz;
                float xy = sx*sy, yz = sy*sz, xz = sx*sz;
                float bb[16];
                bb[0]  = 0.28209479177387814f;
                bb[1]  = -0.4886025119029199f * sy;
                bb[2]  =  0.4886025119029199f * sz;
                bb[3]  = -0.4886025119029199f * sx;
                bb[4]  =  1.0925484305920792f * xy;
                bb[5]  = -1.0925484305920792f * yz;
                bb[6]  =  0.31539156525252005f * (2.f*zz - xx - yy);
                bb[7]  = -1.0925484305920792f * xz;
                bb[8]  =  0.5462742152960396f * (xx - yy);
                bb[9]  = -0.5900435899266435f * sy * (3.f*xx - yy);
                bb[10] =  2.890611442640554f  * xy * sz;
                bb[11] = -0.4570457994644658f * sy * (4.f*zz - xx - yy);
                bb[12] =  0.3731763325901154f * sz * (2.f*zz - 3.f*xx - 3.f*yy);
                bb[13] = -0.4570457994644658f * sx * (4.f*zz - xx - yy);
                bb[14] =  1.445305721320277f  * sz * (xx - yy);
                bb[15] = -0.5900435899266435f * sx * (xx - 3.f*yy);

                float acc0 = 0.f, acc1 = 0.f, acc2 = 0.f;
                const float4* sh4 = (const float4*)(shs + idx*48);
                #pragma unroll
                for (int u = 0; u < 12; ++u) {
                    float4 v = sh4[u];
                    const int f = 4*u;
                    if ((f+0)%3==0) acc0 += bb[(f+0)/3]*v.x; else if ((f+0)%3==1) acc1 += bb[(f+0)/3]*v.x; else acc2 += bb[(f+0)/3]*v.x;
                    if ((f+1)%3==0) acc0 += bb[(f+1)/3]*v.y; else if ((f+1)%3==1) acc1 += bb[(f+1)/3]*v.y; else acc2 += bb[(f+1)/3]*v.y;
                    if ((f+2)%3==0) acc0 += bb[(f+2)/3]*v.z; else if ((f+2)%3==1) acc1 += bb[(f+2)/3]*v.z; else acc2 += bb[(f+2)/3]*v.z;
                    if ((f+3)%3==0) acc0 += bb[(f+3)/3]*v.w; else if ((f+3)%3==1) acc1 += bb[(f+3)/3]*v.w; else acc2 += bb[(f+3)/3]*v.w;
                }

                float* rp = srec + r * 12;
                rp[0] = gxA[idx]; rp[1] = gyA[idx]; rp[2] = cAA[idx]; rp[3] = cBA[idx];
                rp[4] = cCA[idx]; rp[5] = opA[idx];
                rp[6] = fmaxf(acc0 + 0.5f, 0.f);
                rp[7] = fmaxf(acc1 + 0.5f, 0.f);
                rp[8] = fmaxf(acc2 + 0.5f, 0.f);
            }
        }
        __syncthreads();

        // blend: wave 0, sequential LDS reads (affine addresses -> compiler
        // pipelines the ds_reads); per-record early-exit check (R12 showed
        // batching it regresses — saturated tiles die within a few records)
        if (t < 64) {
            int nb = min(CHUNK, M - base);
            for (int j = 0; j < nb; ++j) {
                const float* g = srec + j * 12;
                float4 g0 = *(const float4*)(g);      // gx gy A B
                float4 g1 = *(const float4*)(g + 4);  // C op r g
                float  b2 = g[8];                     // b
                float dx = g0.x - px, dy = g0.y - py;
                float power = -0.5f * (g0.z*dx*dx + g1.x*dy*dy) - g0.w*dx*dy;
                float alpha = fminf(0.99f, g1.y * __expf(power));
                if (live && power <= 0.0f && alpha >= (1.0f/255.0f)) {
                    float Tnew = T * (1.0f - alpha);
                    if (Tnew < 1e-4f) {
                        live = false;          // exact: ae_j and all later ae are 0
                    } else {
                        float w = T * alpha;
                        cr += w * g1.z; cg += w * g1.w; cb += w * b2;
                        Tfin *= (1.0f - alpha);
                        T = Tnew;
                    }
                }
                if (__ballot(live) == 0ull) break;
            }
            if (__ballot(live) == 0ull && t == 0) allDead = 1;
        }
        __syncthreads();
        if (allDead) break;                   // block-uniform after barrier
    }

    if (t < 64) {
        int p = (int)py * W_IMG + (int)px;
        out[p]                 = cr + bg[0] * Tfin;
        out[H_IMG*W_IMG + p]   = cg + bg[1] * Tfin;
        out[2*H_IMG*W_IMG + p] = cb + bg[2] * Tfin;
    }
}

extern "C" void kernel_launch(void* const* d_in, const int* in_sizes, int n_in,
                              void* d_out, int out_size, void* d_ws, size_t ws_size,
                              hipStream_t stream) {
    const float* means3D = (const float*)d_in[0];
    const float* opac    = (const float*)d_in[2];
    const float* shs     = (const float*)d_in[3];
    const float* scales  = (const float*)d_in[4];
    const float* rot     = (const float*)d_in[5];
    const float* vm      = (const float*)d_in[6];
    const float* pm      = (const float*)d_in[7];
    const float* campos  = (const float*)d_in[8];
    const float* bg      = (const float*)d_in[9];

    gauss_tile_kernel<<<N_TILES, NT, 0, stream>>>(
        means3D, opac, shs, scales, rot, vm, pm, campos, bg, (float*)d_out);
}